// Round 14
// baseline (10664.162 us; speedup 1.0000x reference)
//
#include <hip/hip_runtime.h>
#include <hip/hip_cooperative_groups.h>

namespace cg = cooperative_groups;

#define NN 2048
#define NB 32
#define NT 500
#define WGS 1024
#define NWG 256

// Persistent cooperative kernel. R14 = R11 structure with a DECOUPLED
// consumer: only wave 0 polls readiness (coalesced dwordx4 coherent loads of
// the 1024-entry epoch array, s_sleep backoff); the other 15 waves idle at
// the barrier (no issue, no fabric traffic). Payload then fetched by all
// 1024 threads in parallel (one relaxed-atomic u64 each, single round trip).
// Producer path, FMA body, combine order, record path == R8/R11 (validated,
// bit-exact). No cache-invalidating fences (R4 lesson), no placement
// assumptions (R12 lesson).
//
// Safety: producer does payload store_coh8 -> vmcnt(0) -> epoch store (R8-
// validated). Consumer confirms ALL epochs >= step before any payload load.
// Cumulative-epoch transitive argument covers buffer overwrite (2-step skew
// impossible). Replay-safe: epochs re-zeroed in init before one cg
// grid.sync; step 0 skips the exchange (spikes known all-zero).
//
// ws: buf u64[2][1024] @0 (16 KB) | ep u32[1024] @16384 (4 KB) |
//     xT f32[500][32] @20480 (64 KB) | wgpart i32[256] @84480

__device__ __forceinline__ void store_coh8(void* p, unsigned long long v) {
    asm volatile("global_store_dwordx2 %0, %1, off sc0 sc1"
                 :: "v"(p), "v"(v) : "memory");
}
__device__ __forceinline__ uint4 load_coh16(const void* p) {
    uint4 v;
    asm volatile("global_load_dwordx4 %0, %1, off sc0 sc1\n\t"
                 "s_waitcnt vmcnt(0)"
                 : "=&v"(v) : "v"(p) : "memory");
    return v;
}

__launch_bounds__(WGS, 4)
__global__ void reservoir_kernel(const float* __restrict__ x,
                                 const float* __restrict__ W,
                                 const float* __restrict__ bias,
                                 float* __restrict__ out,
                                 void* __restrict__ wsv)
{
    cg::grid_group grid = cg::this_grid();

    __shared__ unsigned int lbits[NN];      // 8 KB spike bits
    __shared__ float lpart[8][8][32];       // 8 KB [jh][row][b]
    __shared__ float lout[2][NB][9];        // padded output stage
    __shared__ int   lcnt[4];

    unsigned long long* buf = (unsigned long long*)wsv;              // [2][1024]
    unsigned int* ep  = (unsigned int*)((char*)wsv + 16384);         // [1024]
    float* xT         = (float*)((char*)wsv + 20480);                // [500][32]
    int*   wgpart     = (int*)((char*)wsv + 84480);                  // [256]

    const int wg = blockIdx.x;
    const int t  = threadIdx.x;
    const int i0 = wg * 8;

    // init: zero epochs (replay safety); transpose x
    { int g = wg * WGS + t;
      if (g < 1024)
          __hip_atomic_store(&ep[g], 0u, __ATOMIC_RELAXED, __HIP_MEMORY_SCOPE_AGENT);
      for (; g < NT * NB; g += NWG * WGS)
          xT[g] = x[(size_t)(g & 31) * NT + (g >> 5)]; }

    // compute identity (== R7/R8/R11): 2 rows per thread
    const int rh = t >> 8;          // 0..3 -> rows 2rh, 2rh+1
    const int jh = (t >> 5) & 7;    // chunk 0..7
    const int b  = t & 31;          // batch

    const float4* __restrict__ wr0 = (const float4*)(W + (size_t)(i0 + 2 * rh    ) * NN) + jh * 64;
    const float4* __restrict__ wr1 = (const float4*)(W + (size_t)(i0 + 2 * rh + 1) * NN) + jh * 64;

    // combine identity (t < 256): (row cil, batch cb), state in registers
    const int cil = t >> 5;
    const int cb  = t & 31;
    const float biasv = (t < 256) ? bias[i0 + cil] : 0.0f;
    float mem = 0.0f;
    int   scount = 0;

    float* spk_rec = out + 1;
    float* mem_rec = out + 1 + (size_t)NT * NB * NN;

    grid.sync();   // init visibility (once)

    for (int step = 0; step < NT; ++step) {
        const int pcur = step & 1;

        if (step == 0) {
            // spikes known all-zero: no exchange
            ((uint2*)lbits)[t] = make_uint2(0u, 0u);
            __syncthreads();   // match (P) barrier position
        } else {
            // (P) only wave 0 polls; waves 1..15 idle at this barrier
            if (t < 64) {
                const unsigned int st = (unsigned int)step;
                #pragma unroll
                for (int q = 0; q < 4; ++q) {
                    const void* pa = &ep[q * 256 + t * 4];
                    for (;;) {
                        uint4 e = load_coh16(pa);
                        if (e.x >= st && e.y >= st && e.z >= st && e.w >= st) break;
                        __builtin_amdgcn_s_sleep(2);
                    }
                }
            }
            __syncthreads();   // (P) all epochs confirmed

            // payload: one relaxed-atomic u64 per thread, parallel round trip
            unsigned long long v =
                __hip_atomic_load(&buf[(size_t)pcur * 1024 + t],
                                  __ATOMIC_RELAXED, __HIP_MEMORY_SCOPE_AGENT);
            *(unsigned long long*)&lbits[2 * t] = v;
        }
        const float xv = (t < 256) ? xT[step * NB + cb] : 0.0f;
        __syncthreads();   // (B) lbits staged

        // chunk partial: 2 rows x 1 batch over 256 consecutive j (bit-exact order)
        float c0 = 0.0f, c1 = 0.0f;
        const uint4* bp = ((const uint4*)lbits) + jh * 64;
        #pragma unroll 4
        for (int jj = 0; jj < 64; ++jj) {
            const float4 w0 = wr0[jj];
            const float4 w1 = wr1[jj];
            const uint4  bu = bp[jj];
            float s;
            s = (float)((bu.x >> b) & 1u); c0 = fmaf(w0.x, s, c0); c1 = fmaf(w1.x, s, c1);
            s = (float)((bu.y >> b) & 1u); c0 = fmaf(w0.y, s, c0); c1 = fmaf(w1.y, s, c1);
            s = (float)((bu.z >> b) & 1u); c0 = fmaf(w0.z, s, c0); c1 = fmaf(w1.z, s, c1);
            s = (float)((bu.w >> b) & 1u); c0 = fmaf(w0.w, s, c0); c1 = fmaf(w1.w, s, c1);
        }
        lpart[jh][2 * rh    ][b] = c0;
        lpart[jh][2 * rh + 1][b] = c1;
        __syncthreads();   // (C) lpart ready

        if (t < 256) {
            // sequential combine over chunks (bit-exact validated order)
            float d = lpart[0][cil][cb];
            #pragma unroll
            for (int k = 1; k < 8; ++k) d += lpart[k][cil][cb];

            const float sp = (float)((lbits[i0 + cil] >> cb) & 1u);

            float base = 0.95f * mem + xv + d + biasv;
            float nm   = base * (1.0f - sp);
            float ns   = (nm > 1.0f) ? 1.0f : 0.0f;
            mem = nm;
            scount += (int)ns;

            // publish: one coherent 8B store per wave -> vmcnt -> epoch store
            unsigned long long bal = __ballot(ns > 0.5f);  // lo32=row 2w2, hi32=row 2w2+1
            const int l  = t & 63;
            const int w2 = t >> 6;
            const int pnxt = pcur ^ 1;
            if (l == 0)
                store_coh8((char*)(buf + (size_t)pnxt * 1024) + 8 * (4 * wg + w2), bal);
            asm volatile("s_waitcnt vmcnt(0)" ::: "memory");
            if (l == 0)
                __hip_atomic_store(&ep[4 * wg + w2], (unsigned int)(step + 1),
                                   __ATOMIC_RELAXED, __HIP_MEMORY_SCOPE_AGENT);

            lout[0][cb][cil] = ns;
            lout[1][cb][cil] = nm;
        }
        __syncthreads();   // (D) lout staged

        // record stores: LDS-staged, nontemporal (keeps W in L2 -- R10 lesson)
        if (t < 512) {
            const int arr = t >> 8;
            const int r2  = t & 255;
            const int bb  = r2 >> 3;
            const int il  = r2 & 7;
            size_t o = ((size_t)step * NB + bb) * (size_t)NN + i0 + il;
            if (arr == 0) __builtin_nontemporal_store(lout[0][bb][il], &spk_rec[o]);
            else          __builtin_nontemporal_store(lout[1][bb][il], &mem_rec[o]);
        }
    }

    // average firing rate (scount==0 for t>=256)
    #pragma unroll
    for (int d2 = 1; d2 < 64; d2 <<= 1) scount += __shfl_xor(scount, d2, 64);
    if ((t & 63) == 0 && t < 256) lcnt[t >> 6] = scount;
    __syncthreads();
    if (t == 0) wgpart[wg] = lcnt[0] + lcnt[1] + lcnt[2] + lcnt[3];
    grid.sync();
    if (wg == 0) {
        int ps = (t < NWG) ? wgpart[t] : 0;
        #pragma unroll
        for (int d2 = 1; d2 < 64; d2 <<= 1) ps += __shfl_xor(ps, d2, 64);
        if ((t & 63) == 0 && t < 256) lcnt[t >> 6] = ps;
        __syncthreads();
        if (t == 0) {
            long long s2 = (long long)lcnt[0] + lcnt[1] + lcnt[2] + lcnt[3];
            out[0] = (float)((double)s2 / (double)((long long)NT * NB * NN));
        }
    }
}

extern "C" void kernel_launch(void* const* d_in, const int* in_sizes, int n_in,
                              void* d_out, int out_size, void* d_ws, size_t ws_size,
                              hipStream_t stream) {
    const float* x    = (const float*)d_in[0];  // (32, 500, 1)
    const float* W    = (const float*)d_in[1];  // (2048, 2048)
    const float* bias = (const float*)d_in[2];  // (2048,)
    float* out = (float*)d_out;
    void*  ws  = d_ws;

    void* args[] = { (void*)&x, (void*)&W, (void*)&bias, (void*)&out, (void*)&ws };
    hipLaunchCooperativeKernel((const void*)reservoir_kernel,
                               dim3(NWG), dim3(WGS), args, 0, stream);
}